// Round 1
// baseline (896.516 us; speedup 1.0000x reference)
//
#include <hip/hip_runtime.h>
#include <hip/hip_bf16.h>
#include <hip/hip_cooperative_groups.h>

namespace cg = cooperative_groups;

#define B_   64
#define CIN  2048
#define COUT 32
#define P    196      // 14*14
#define PPAD 224      // padded pixel count
#define REP  1024
#define K1   (CIN*COUT)  // 65536

typedef float  f32x4  __attribute__((ext_vector_type(4)));
typedef __bf16 bf16x8 __attribute__((ext_vector_type(8)));
typedef __bf16 bf16x4 __attribute__((ext_vector_type(4)));

// ---- workspace layout (bytes) ----
#define OFF_W2     0                 // bf16 [9*32][2048]    (1.18MB)
#define OFF_AM     1310720           // f32  [64][32][224]   (1.84MB)
#define OFF_POOLED 3145728           // bf16 [64][65536]     (8.39MB)
#define OFF_S1     11534336          // f32  [64][64][1024]  (16.8MB)
#define OFF_H6B    28311552          // bf16 [64][1024]      (131KB)
#define OFF_S2     28442624          // f32  [8][64][1024]   (2.1MB)

static __device__ __forceinline__ f32x4 mfma16(bf16x8 a, bf16x8 b, f32x4 c) {
  return __builtin_amdgcn_mfma_f32_16x16x32_bf16(a, b, c, 0, 0, 0);
}

#define ICW 72   // LDS row stride in elements (64 ic + 8 pad -> conflict-free)

// ============================================================
// ONE cooperative megakernel: 512 blocks x 256 threads, 6 grid syncs.
// Phases: prep/zero -> conv -> pooled -> gemm1 -> reduce1 -> gemm2 -> reduce2
// ============================================================
__global__ __launch_bounds__(256, 2)
void mega_kernel(const float* __restrict__ x,  const float* __restrict__ cw,
                 const float* __restrict__ cb, const float* __restrict__ w6,
                 const float* __restrict__ b6, const float* __restrict__ w7,
                 const float* __restrict__ b7,
                 __bf16* __restrict__ W2, float* __restrict__ am,
                 __bf16* __restrict__ pooled, float* __restrict__ S1,
                 __bf16* __restrict__ h6b, float* __restrict__ S2,
                 float* __restrict__ out) {
  __shared__ __bf16 XT[256 * ICW];       // 36.9 KB (conv phase only)
  cg::grid_group grid = cg::this_grid();

  const int blk  = blockIdx.x;           // 0..511
  const int t    = threadIdx.x;          // 0..255
  const int wv   = t >> 6;               // 0..3
  const int lane = t & 63;
  const int q    = lane >> 4, ln = lane & 15;

  // ---------------- phase 0: prep W2 + zero am ----------------
  if (blk < 256) {
    // cw[o][cin][d] f32 -> W2[d*32+o][cin] bf16
    const int o = blk >> 3, cc = blk & 7;
    const int cin = cc * 256 + t;
    const float* src = cw + ((size_t)o * CIN + cin) * 9;
    #pragma unroll
    for (int d = 0; d < 9; d++)
      W2[((size_t)d * COUT + o) * CIN + cin] = (__bf16)src[d];
  } else {
    // zero am: 64*32*224 = 458752 floats = 7 * 65536
    #pragma unroll
    for (int k = 0; k < 7; k++)
      am[(size_t)(blk - 256) * 256 + t + (size_t)k * 65536] = 0.f;
  }
  grid.sync();

  // ---------------- phase 1: conv (implicit GEMM, 8 k-slices x 64 b) -------
  {
    const int ksl = blk & 7;             // 256-cin slice
    const int bb  = blk >> 3;            // batch
    const float* xb = x + (size_t)bb * CIN * P;
    const int kbase = ksl * 256;

    // per-wave pixel geometry: 4 waves x 4 n-tiles of 16 pixels (tiles 0..12 live)
    int rb[4]; bool valid[4]; int pix[4]; bool tv[4];
    #pragma unroll
    for (int nt = 0; nt < 4; nt++) {
      const int tile = wv * 4 + nt;
      const int pt = tile * 16 + ln;
      tv[nt]    = (tile <= 12);          // wave-uniform
      valid[nt] = (pt < P);
      pix[nt]   = pt;
      const int pr = valid[nt] ? pt : 0;
      const int h = pr / 14, w = pr - (pr / 14) * 14;
      rb[nt] = (h + 1) * 16 + (w + 1);   // center-tap ext row
    }
    f32x4 acc[2][4];
    #pragma unroll
    for (int m = 0; m < 2; m++)
      #pragma unroll
      for (int n = 0; n < 4; n++) { f32x4 z = {0.f,0.f,0.f,0.f}; acc[m][n] = z; }

    // zero border rows once (each thread owns one ext row)
    {
      const int row = t, hh = row >> 4, ww = row & 15;
      if (hh == 0 || hh == 15 || ww == 0 || ww == 15) {
        #pragma unroll
        for (int g = 0; g < 8; g++) { bf16x8 z = {}; *(bf16x8*)&XT[row * ICW + g * 8] = z; }
      }
    }

    for (int sub = 0; sub < 4; sub++) {  // 4 sub-chunks of 64 cin
      const int i0 = kbase + sub * 64;
      __syncthreads();                   // prev compute done (covers border init)
      for (int u = t; u < 1568; u += 256) {
        const int g = u / 196, p = u - g * 196;
        const int h = p / 14, w = p - (p / 14) * 14;
        bf16x8 v;
        #pragma unroll
        for (int j = 0; j < 8; j++)
          v[j] = (__bf16)xb[(size_t)(i0 + g * 8 + j) * P + p];
        *(bf16x8*)&XT[((h + 1) * 16 + (w + 1)) * ICW + g * 8] = v;
      }
      __syncthreads();

      #pragma unroll
      for (int ks2 = 0; ks2 < 2; ks2++) {
        const int kg  = i0 + ks2 * 32 + q * 8;
        const int off = (ks2 * 4 + q) * 8;
        #pragma unroll
        for (int d = 0; d < 9; d++) {
          const int dy = d / 3, dx = d - (d / 3) * 3;
          const int delta = (dy - 1) * 16 + (dx - 1);
          bf16x8 a0 = *(const bf16x8*)&W2[(size_t)(d * COUT + ln) * CIN + kg];
          bf16x8 a1 = *(const bf16x8*)&W2[(size_t)(d * COUT + 16 + ln) * CIN + kg];
          #pragma unroll
          for (int nt = 0; nt < 4; nt++) {
            if (tv[nt]) {
              bf16x8 bf = *(const bf16x8*)&XT[(rb[nt] + delta) * ICW + off];
              acc[0][nt] = mfma16(a0, bf, acc[0][nt]);
              acc[1][nt] = mfma16(a1, bf, acc[1][nt]);
            }
          }
        }
      }
    }

    #pragma unroll
    for (int mt = 0; mt < 2; mt++)
      #pragma unroll
      for (int nt = 0; nt < 4; nt++)
        if (valid[nt]) {
          #pragma unroll
          for (int r = 0; r < 4; r++) {
            const int o = mt * 16 + q * 4 + r;
            atomicAdd(&am[((size_t)bb * COUT + o) * PPAD + pix[nt]], acc[mt][nt][r]);
          }
        }
  }
  grid.sync();

  // ---------------- phase 2: pooled (1024 virtual blocks) ----------------
  for (int vv = blk; vv < 1024; vv += 512) {
    const int ig = vv & 15, bb = vv >> 4;
    const int ibase = ig * 128 + wv * 32;

    f32x4 acc[2][2];
    #pragma unroll
    for (int a = 0; a < 2; a++)
      #pragma unroll
      for (int c = 0; c < 2; c++) { f32x4 z = {0.f,0.f,0.f,0.f}; acc[a][c] = z; }

    const float* amb = am + (size_t)bb * COUT * PPAD;
    const float* xb  = x + (size_t)bb * CIN * P;
    const float cbv[2] = { cb[ln], cb[16 + ln] };

    for (int kc = 0; kc < 7; kc++) {
      const int k0 = kc * 32 + q * 8;
      bf16x8 af[2];
      #pragma unroll
      for (int o2 = 0; o2 < 2; o2++) {
        const float* src = &amb[(size_t)(o2 * 16 + ln) * PPAD + k0];
        f32x4 v0 = *(const f32x4*)src;
        f32x4 v1 = *(const f32x4*)(src + 4);
        bf16x8 a;
        #pragma unroll
        for (int j = 0; j < 4; j++) { a[j] = (__bf16)(v0[j] + cbv[o2]); a[4 + j] = (__bf16)(v1[j] + cbv[o2]); }
        af[o2] = a;
      }
      #pragma unroll
      for (int it = 0; it < 2; it++) {
        const int i = ibase + it * 16 + ln;
        bf16x8 bfr;
        if (kc < 6) {
          const float* src = &xb[(size_t)i * P + k0];
          f32x4 v0 = *(const f32x4*)src;
          f32x4 v1 = *(const f32x4*)(src + 4);
          #pragma unroll
          for (int j = 0; j < 4; j++) { bfr[j] = (__bf16)v0[j]; bfr[4 + j] = (__bf16)v1[j]; }
        } else {
          #pragma unroll
          for (int j = 0; j < 8; j++) {
            const int p = k0 + j;
            bfr[j] = (p < P) ? (__bf16)xb[(size_t)i * P + p] : (__bf16)0.f;
          }
        }
        acc[0][it] = mfma16(af[0], bfr, acc[0][it]);
        acc[1][it] = mfma16(af[1], bfr, acc[1][it]);
      }
    }

    const float sc = 1.0f / 196.0f;
    #pragma unroll
    for (int o2 = 0; o2 < 2; o2++)
      #pragma unroll
      for (int it = 0; it < 2; it++) {
        const int i = ibase + it * 16 + ln;
        bf16x4 vvv;
        #pragma unroll
        for (int r = 0; r < 4; r++) vvv[r] = (__bf16)(acc[o2][it][r] * sc);
        *(bf16x4*)&pooled[(size_t)bb * K1 + (size_t)i * COUT + o2 * 16 + q * 4] = vvv;
      }
  }
  grid.sync();

  // ---------------- phase 3: gemm1 (1024 virtual blocks) ----------------
  for (int vv = blk; vv < 1024; vv += 512) {
    const int nb = vv & 15, ks = vv >> 4;
    const int n0 = nb * 64 + wv * 16;
    const int kbase = ks * 1024;

    f32x4 acc[4];
    #pragma unroll
    for (int a = 0; a < 4; a++) { f32x4 z = {0.f,0.f,0.f,0.f}; acc[a] = z; }

    #pragma unroll 2
    for (int kc = 0; kc < 32; kc++) {
      const int k0 = kbase + kc * 32 + q * 8;
      const float* src = &w6[(size_t)(n0 + ln) * K1 + k0];
      f32x4 v0 = *(const f32x4*)src;
      f32x4 v1 = *(const f32x4*)(src + 4);
      bf16x8 bfr;
      #pragma unroll
      for (int j = 0; j < 4; j++) { bfr[j] = (__bf16)v0[j]; bfr[4 + j] = (__bf16)v1[j]; }
      #pragma unroll
      for (int mi = 0; mi < 4; mi++) {
        bf16x8 af = *(const bf16x8*)&pooled[(size_t)(mi * 16 + ln) * K1 + k0];
        acc[mi] = mfma16(af, bfr, acc[mi]);
      }
    }
    #pragma unroll
    for (int mi = 0; mi < 4; mi++)
      #pragma unroll
      for (int r = 0; r < 4; r++)
        S1[(size_t)ks * (B_ * REP) + (size_t)(mi * 16 + q * 4 + r) * REP + n0 + ln] = acc[mi][r];
  }
  grid.sync();

  // ---------------- phase 4: reduce1 -> h6b ----------------
  if (blk < 256) {
    const int idx = blk * 256 + t;
    float s = 0.f;
    #pragma unroll 8
    for (int ks = 0; ks < 64; ks++) s += S1[(size_t)ks * (B_ * REP) + idx];
    h6b[idx] = (__bf16)fmaxf(s + b6[idx & (REP - 1)], 0.f);
  }
  grid.sync();

  // ---------------- phase 5: gemm2 (8 k-slices of 128) ----------------
  if (blk < 128) {
    const int nb = blk & 15, ks = blk >> 4;   // ks 0..7
    const int n0 = nb * 64 + wv * 16;

    f32x4 acc[4];
    #pragma unroll
    for (int a = 0; a < 4; a++) { f32x4 z = {0.f,0.f,0.f,0.f}; acc[a] = z; }

    #pragma unroll
    for (int kc = 0; kc < 4; kc++) {
      const int k0 = ks * 128 + kc * 32 + q * 8;
      const float* src = &w7[(size_t)(n0 + ln) * REP + k0];
      f32x4 v0 = *(const f32x4*)src;
      f32x4 v1 = *(const f32x4*)(src + 4);
      bf16x8 bfr;
      #pragma unroll
      for (int j = 0; j < 4; j++) { bfr[j] = (__bf16)v0[j]; bfr[4 + j] = (__bf16)v1[j]; }
      #pragma unroll
      for (int mi = 0; mi < 4; mi++) {
        bf16x8 af = *(const bf16x8*)&h6b[(size_t)(mi * 16 + ln) * REP + k0];
        acc[mi] = mfma16(af, bfr, acc[mi]);
      }
    }
    #pragma unroll
    for (int mi = 0; mi < 4; mi++)
      #pragma unroll
      for (int r = 0; r < 4; r++)
        S2[(size_t)ks * (B_ * REP) + (size_t)(mi * 16 + q * 4 + r) * REP + n0 + ln] = acc[mi][r];
  }
  grid.sync();

  // ---------------- phase 6: reduce2 -> out ----------------
  if (blk < 256) {
    const int idx = blk * 256 + t;
    float s = 0.f;
    #pragma unroll
    for (int ks = 0; ks < 8; ks++) s += S2[(size_t)ks * (B_ * REP) + idx];
    out[idx] = fmaxf(s + b7[idx & (REP - 1)], 0.f);
  }
}

extern "C" void kernel_launch(void* const* d_in, const int* in_sizes, int n_in,
                              void* d_out, int out_size, void* d_ws, size_t ws_size,
                              hipStream_t stream) {
  const float* x   = (const float*)d_in[0];
  const float* cw  = (const float*)d_in[1];
  const float* cb  = (const float*)d_in[2];
  const float* w6  = (const float*)d_in[3];
  const float* b6  = (const float*)d_in[4];
  const float* w7  = (const float*)d_in[5];
  const float* b7  = (const float*)d_in[6];
  float* out = (float*)d_out;

  char* ws = (char*)d_ws;
  __bf16* W2     = (__bf16*)(ws + OFF_W2);
  float*  am     = (float*)(ws + OFF_AM);
  __bf16* pooled = (__bf16*)(ws + OFF_POOLED);
  float*  S1     = (float*)(ws + OFF_S1);
  __bf16* h6b    = (__bf16*)(ws + OFF_H6B);
  float*  S2     = (float*)(ws + OFF_S2);

  void* args[] = { (void*)&x, (void*)&cw, (void*)&cb, (void*)&w6, (void*)&b6,
                   (void*)&w7, (void*)&b7, (void*)&W2, (void*)&am, (void*)&pooled,
                   (void*)&S1, (void*)&h6b, (void*)&S2, (void*)&out };
  hipLaunchCooperativeKernel(reinterpret_cast<void*>(mega_kernel),
                             dim3(512), dim3(256), args, 0, stream);
}

// Round 2
// 572.729 us; speedup vs baseline: 1.5653x; 1.5653x over previous
//
#include <hip/hip_runtime.h>
#include <hip/hip_bf16.h>

#define B_   64
#define CIN  2048
#define COUT 32
#define P    196      // 14*14
#define PPAD 224      // padded pixel count
#define REP  1024
#define K1   (CIN*COUT)  // 65536
#define NSL  16          // conv cin slices (128 cin each)

typedef float  f32x4  __attribute__((ext_vector_type(4)));
typedef __bf16 bf16x8 __attribute__((ext_vector_type(8)));
typedef __bf16 bf16x4 __attribute__((ext_vector_type(4)));

// ---- workspace layout (bytes) ----
#define OFF_W2     0                 // bf16 [9*32][2048]        (1.18MB)
#define OFF_AMP    1179648           // f32  [16][64][32][224]   (29.4MB)
#define OFF_AMBF   30539776          // bf16 [64][32][224]       (0.92MB)
#define OFF_POOLED 31457280          // bf16 [64][65536]         (8.39MB)
#define OFF_S1     39845888          // f32  [32][64][1024]      (8.39MB)
#define OFF_H6B    48234496          // bf16 [64][1024]          (131KB)
#define OFF_S2     48365568          // f32  [8][64][1024]       (2.1MB)

static __device__ __forceinline__ f32x4 mfma16(bf16x8 a, bf16x8 b, f32x4 c) {
  return __builtin_amdgcn_mfma_f32_16x16x32_bf16(a, b, c, 0, 0, 0);
}

// ============================================================
// prep_w2: cw[o][cin][d] f32 -> W2[d*32+o][cin] bf16
// ============================================================
__global__ __launch_bounds__(256)
void prep_w2(const float* __restrict__ cw, __bf16* __restrict__ W2) {
  const int blk = blockIdx.x;            // o*8 + cc
  const int o = blk >> 3, cc = blk & 7;
  const int cin = cc * 256 + threadIdx.x;
  const float* src = cw + ((size_t)o * CIN + cin) * 9;
  #pragma unroll
  for (int d = 0; d < 9; d++)
    W2[((size_t)d * COUT + o) * CIN + cin] = (__bf16)src[d];
}

// ============================================================
// conv: per-slice partials, no atomics. grid (16 ksl, 64 b), 448 thr.
// Register double-buffer: sub s+1 global loads issue before sub s MFMA.
// ============================================================
#define ICW 72   // LDS row stride (64 ic + 8 pad -> conflict-free)
__global__ __launch_bounds__(448)
void conv_kernel(const float* __restrict__ x, const __bf16* __restrict__ W2,
                 float* __restrict__ amp) {
  __shared__ __bf16 XT[256 * ICW];       // 36.9 KB

  const int ksl = blockIdx.x;            // 128-cin slice
  const int bb  = blockIdx.y;
  const int t   = threadIdx.x;
  const int wv  = t >> 6;                // 0..6
  const int lane = t & 63;
  const int q = lane >> 4, ln = lane & 15;
  const float* xb = x + (size_t)bb * CIN * P;
  const int kbase = ksl * 128;

  // per-wave pixel geometry (2 n-tiles of 16 pixels; 7 waves cover 224)
  int rb[2]; bool valid[2]; int pix[2];
  #pragma unroll
  for (int nt = 0; nt < 2; nt++) {
    const int pt = wv * 32 + nt * 16 + ln;
    pix[nt] = pt; valid[nt] = (pt < P);
    const int pr = valid[nt] ? pt : 0;
    const int h = pr / 14, w = pr - (pr / 14) * 14;
    rb[nt] = (h + 1) * 16 + (w + 1);
  }
  f32x4 acc[2][2];
  #pragma unroll
  for (int m = 0; m < 2; m++)
    #pragma unroll
    for (int n = 0; n < 2; n++) { f32x4 z = {0.f,0.f,0.f,0.f}; acc[m][n] = z; }

  // staging geometry: u = t + 448*it  (sub-invariant)
  const int nIter = (t < 224) ? 4 : 3;
  int obase[4], dst[4];
  #pragma unroll
  for (int it = 0; it < 4; it++) {
    const int u = t + 448 * it;
    if (u < 1568) {
      const int g = u / 196, p = u - g * 196;
      const int h = p / 14, w = p - (p / 14) * 14;
      obase[it] = (g * 8) * P + p;
      dst[it]   = ((h + 1) * 16 + (w + 1)) * ICW + g * 8;
    } else { obase[it] = 0; dst[it] = 0; }
  }

  bf16x8 pre[4];
  // ---- LOAD sub 0 (issue early) ----
  #pragma unroll
  for (int it = 0; it < 4; it++)
    if (it < nIter) {
      bf16x8 v;
      #pragma unroll
      for (int j = 0; j < 8; j++)
        v[j] = (__bf16)xb[(size_t)kbase * P + obase[it] + j * P];
      pre[it] = v;
    }

  // border rows zero (disjoint from interior staging writes)
  if (t < 256) {
    const int hh = t >> 4, ww = t & 15;
    if (hh == 0 || hh == 15 || ww == 0 || ww == 15) {
      #pragma unroll
      for (int g = 0; g < 8; g++) { bf16x8 z = {}; *(bf16x8*)&XT[t * ICW + g * 8] = z; }
    }
  }

  // ---- WRITE sub 0 ----
  #pragma unroll
  for (int it = 0; it < 4; it++)
    if (it < nIter) *(bf16x8*)&XT[dst[it]] = pre[it];

  // ---- LOAD sub 1 (hides under barrier + compute 0) ----
  #pragma unroll
  for (int it = 0; it < 4; it++)
    if (it < nIter) {
      bf16x8 v;
      #pragma unroll
      for (int j = 0; j < 8; j++)
        v[j] = (__bf16)xb[(size_t)(kbase + 64) * P + obase[it] + j * P];
      pre[it] = v;
    }

  __syncthreads();

  #pragma unroll
  for (int sub = 0; sub < 2; sub++) {
    const int i0 = kbase + sub * 64;
    // ---- COMPUTE sub ----
    #pragma unroll
    for (int ks2 = 0; ks2 < 2; ks2++) {
      const int kg  = i0 + ks2 * 32 + q * 8;
      const int off = (ks2 * 4 + q) * 8;
      #pragma unroll
      for (int d = 0; d < 9; d++) {
        const int dy = d / 3, dx = d - (d / 3) * 3;
        const int delta = (dy - 1) * 16 + (dx - 1);
        bf16x8 a0 = *(const bf16x8*)&W2[(size_t)(d * COUT + ln) * CIN + kg];
        bf16x8 a1 = *(const bf16x8*)&W2[(size_t)(d * COUT + 16 + ln) * CIN + kg];
        #pragma unroll
        for (int nt = 0; nt < 2; nt++) {
          bf16x8 bf = *(const bf16x8*)&XT[(rb[nt] + delta) * ICW + off];
          acc[0][nt] = mfma16(a0, bf, acc[0][nt]);
          acc[1][nt] = mfma16(a1, bf, acc[1][nt]);
        }
      }
    }
    if (sub == 0) {
      __syncthreads();                   // compute 0 done before overwrite
      #pragma unroll
      for (int it = 0; it < 4; it++)
        if (it < nIter) *(bf16x8*)&XT[dst[it]] = pre[it];
      __syncthreads();                   // writes visible
    }
  }

  // epilogue: direct stores to this slice's partial
  float* dstp = amp + (((size_t)ksl * B_ + bb) * COUT) * PPAD;
  #pragma unroll
  for (int mt = 0; mt < 2; mt++)
    #pragma unroll
    for (int nt = 0; nt < 2; nt++)
      if (valid[nt]) {
        #pragma unroll
        for (int r = 0; r < 4; r++) {
          const int o = mt * 16 + q * 4 + r;
          dstp[(size_t)o * PPAD + pix[nt]] = acc[mt][nt][r];
        }
      }
}

// ============================================================
// am_final: am_bf[b][o][p] = bf16(sum_sl amp + cb[o]); pad region -> 0
// ============================================================
__global__ __launch_bounds__(256)
void am_final_kernel(const float* __restrict__ amp, const float* __restrict__ cb,
                     __bf16* __restrict__ am_bf) {
  const int NE = B_ * COUT * PPAD;       // 458752
  for (int e = blockIdx.x * 256 + threadIdx.x; e < NE; e += 448 * 256) {
    const int row = e / PPAD;            // b*32+o
    const int pe  = e - row * PPAD;
    float v = 0.f;
    if (pe < P) {
      float s = 0.f;
      #pragma unroll
      for (int sl = 0; sl < NSL; sl++) s += amp[(size_t)sl * NE + e];
      v = s + cb[row & (COUT - 1)];
    }
    am_bf[e] = (__bf16)v;
  }
}

// ============================================================
// pooled[b][i*32+o] = bf16( (1/196) sum_p am_bf[b,o,p] * x[b,i,p] )
// grid (16, 64), block 256; am pad region is zero.
// ============================================================
__global__ __launch_bounds__(256)
void pooled_kernel(const float* __restrict__ x, const __bf16* __restrict__ amb_,
                   __bf16* __restrict__ pooled) {
  const int b  = blockIdx.y;
  const int ig = blockIdx.x;
  const int t  = threadIdx.x;
  const int wv = t >> 6;
  const int lane = t & 63;
  const int q = lane >> 4, ln = lane & 15;
  const int ibase = ig * 128 + wv * 32;

  f32x4 acc[2][2];
  #pragma unroll
  for (int a = 0; a < 2; a++)
    #pragma unroll
    for (int c = 0; c < 2; c++) { f32x4 z = {0.f,0.f,0.f,0.f}; acc[a][c] = z; }

  const __bf16* amb = amb_ + (size_t)b * COUT * PPAD;
  const float*  xb  = x + (size_t)b * CIN * P;

  #pragma unroll
  for (int kc = 0; kc < 7; kc++) {
    const int k0 = kc * 32 + q * 8;
    bf16x8 af[2];
    #pragma unroll
    for (int o2 = 0; o2 < 2; o2++)
      af[o2] = *(const bf16x8*)&amb[(size_t)(o2 * 16 + ln) * PPAD + k0];
    #pragma unroll
    for (int it = 0; it < 2; it++) {
      const int i = ibase + it * 16 + ln;
      bf16x8 bfr;
      if (kc < 6) {
        const float* src = &xb[(size_t)i * P + k0];
        f32x4 v0 = *(const f32x4*)src;
        f32x4 v1 = *(const f32x4*)(src + 4);
        #pragma unroll
        for (int j = 0; j < 4; j++) { bfr[j] = (__bf16)v0[j]; bfr[4 + j] = (__bf16)v1[j]; }
      } else {
        #pragma unroll
        for (int j = 0; j < 8; j++) {
          const int p = k0 + j;
          bfr[j] = (p < P) ? (__bf16)xb[(size_t)i * P + p] : (__bf16)0.f;
        }
      }
      acc[0][it] = mfma16(af[0], bfr, acc[0][it]);
      acc[1][it] = mfma16(af[1], bfr, acc[1][it]);
    }
  }

  const float sc = 1.0f / 196.0f;
  #pragma unroll
  for (int o2 = 0; o2 < 2; o2++)
    #pragma unroll
    for (int it = 0; it < 2; it++) {
      const int i = ibase + it * 16 + ln;
      bf16x4 vv;
      #pragma unroll
      for (int r = 0; r < 4; r++) vv[r] = (__bf16)(acc[o2][it][r] * sc);
      *(bf16x4*)&pooled[(size_t)b * K1 + (size_t)i * COUT + o2 * 16 + q * 4] = vv;
    }
}

// ============================================================
// gemm1: S1[ks][m][n] partials, K=2048 per slice. grid (16 nb, 32 ks), 256 thr.
// ============================================================
__global__ __launch_bounds__(256)
void gemm1_kernel(const __bf16* __restrict__ pooled, const float* __restrict__ w6,
                  float* __restrict__ S1) {
  const int nb = blockIdx.x, ks = blockIdx.y;
  const int t = threadIdx.x;
  const int wv = t >> 6;
  const int lane = t & 63;
  const int q = lane >> 4, ln = lane & 15;
  const int n0 = nb * 64 + wv * 16;
  const int kbase = ks * 2048;

  f32x4 acc[4];
  #pragma unroll
  for (int a = 0; a < 4; a++) { f32x4 z = {0.f,0.f,0.f,0.f}; acc[a] = z; }

  #pragma unroll 4
  for (int kc = 0; kc < 64; kc++) {
    const int k0 = kbase + kc * 32 + q * 8;
    const float* src = &w6[(size_t)(n0 + ln) * K1 + k0];
    f32x4 v0 = *(const f32x4*)src;
    f32x4 v1 = *(const f32x4*)(src + 4);
    bf16x8 bfr;
    #pragma unroll
    for (int j = 0; j < 4; j++) { bfr[j] = (__bf16)v0[j]; bfr[4 + j] = (__bf16)v1[j]; }
    #pragma unroll
    for (int mi = 0; mi < 4; mi++) {
      bf16x8 af = *(const bf16x8*)&pooled[(size_t)(mi * 16 + ln) * K1 + k0];
      acc[mi] = mfma16(af, bfr, acc[mi]);
    }
  }
  #pragma unroll
  for (int mi = 0; mi < 4; mi++)
    #pragma unroll
    for (int r = 0; r < 4; r++)
      S1[(size_t)ks * (B_ * REP) + (size_t)(mi * 16 + q * 4 + r) * REP + n0 + ln] = acc[mi][r];
}

// ============================================================
// reduce1: h6b[m][n] = bf16(relu(sum_ks S1 + b6[n]))
// ============================================================
__global__ __launch_bounds__(256)
void reduce1_kernel(const float* __restrict__ S1, const float* __restrict__ b6,
                    __bf16* __restrict__ h6b) {
  const int idx = blockIdx.x * 256 + threadIdx.x;
  float s = 0.f;
  #pragma unroll 8
  for (int ks = 0; ks < 32; ks++) s += S1[(size_t)ks * (B_ * REP) + idx];
  h6b[idx] = (__bf16)fmaxf(s + b6[idx & (REP - 1)], 0.f);
}

// ============================================================
// gemm2: S2[ks][m][n] partials, K=128 per slice. grid (16 nb, 8 ks), 256 thr.
// ============================================================
__global__ __launch_bounds__(256)
void gemm2_kernel(const __bf16* __restrict__ h6b, const float* __restrict__ w7,
                  float* __restrict__ S2) {
  const int nb = blockIdx.x, ks = blockIdx.y;
  const int t = threadIdx.x;
  const int wv = t >> 6;
  const int lane = t & 63;
  const int q = lane >> 4, ln = lane & 15;
  const int n0 = nb * 64 + wv * 16;

  f32x4 acc[4];
  #pragma unroll
  for (int a = 0; a < 4; a++) { f32x4 z = {0.f,0.f,0.f,0.f}; acc[a] = z; }

  #pragma unroll
  for (int kc = 0; kc < 4; kc++) {
    const int k0 = ks * 128 + kc * 32 + q * 8;
    const float* src = &w7[(size_t)(n0 + ln) * REP + k0];
    f32x4 v0 = *(const f32x4*)src;
    f32x4 v1 = *(const f32x4*)(src + 4);
    bf16x8 bfr;
    #pragma unroll
    for (int j = 0; j < 4; j++) { bfr[j] = (__bf16)v0[j]; bfr[4 + j] = (__bf16)v1[j]; }
    #pragma unroll
    for (int mi = 0; mi < 4; mi++) {
      bf16x8 af = *(const bf16x8*)&h6b[(size_t)(mi * 16 + ln) * REP + k0];
      acc[mi] = mfma16(af, bfr, acc[mi]);
    }
  }
  #pragma unroll
  for (int mi = 0; mi < 4; mi++)
    #pragma unroll
    for (int r = 0; r < 4; r++)
      S2[(size_t)ks * (B_ * REP) + (size_t)(mi * 16 + q * 4 + r) * REP + n0 + ln] = acc[mi][r];
}

// ============================================================
// reduce2: out[m][n] = relu(sum_ks S2 + b7[n])
// ============================================================
__global__ __launch_bounds__(256)
void reduce2_kernel(const float* __restrict__ S2, const float* __restrict__ b7,
                    float* __restrict__ out) {
  const int idx = blockIdx.x * 256 + threadIdx.x;
  float s = 0.f;
  #pragma unroll
  for (int ks = 0; ks < 8; ks++) s += S2[(size_t)ks * (B_ * REP) + idx];
  out[idx] = fmaxf(s + b7[idx & (REP - 1)], 0.f);
}

extern "C" void kernel_launch(void* const* d_in, const int* in_sizes, int n_in,
                              void* d_out, int out_size, void* d_ws, size_t ws_size,
                              hipStream_t stream) {
  const float* x   = (const float*)d_in[0];
  const float* cw  = (const float*)d_in[1];
  const float* cb  = (const float*)d_in[2];
  const float* w6  = (const float*)d_in[3];
  const float* b6  = (const float*)d_in[4];
  const float* w7  = (const float*)d_in[5];
  const float* b7  = (const float*)d_in[6];
  float* out = (float*)d_out;

  char* ws = (char*)d_ws;
  __bf16* W2     = (__bf16*)(ws + OFF_W2);
  float*  amp    = (float*)(ws + OFF_AMP);
  __bf16* am_bf  = (__bf16*)(ws + OFF_AMBF);
  __bf16* pooled = (__bf16*)(ws + OFF_POOLED);
  float*  S1     = (float*)(ws + OFF_S1);
  __bf16* h6b    = (__bf16*)(ws + OFF_H6B);
  float*  S2     = (float*)(ws + OFF_S2);

  prep_w2        <<<256,          256, 0, stream>>>(cw, W2);
  conv_kernel    <<<dim3(16, 64), 448, 0, stream>>>(x, W2, amp);
  am_final_kernel<<<448,          256, 0, stream>>>(amp, cb, am_bf);
  pooled_kernel  <<<dim3(16, 64), 256, 0, stream>>>(x, am_bf, pooled);
  gemm1_kernel   <<<dim3(16, 32), 256, 0, stream>>>(pooled, w6, S1);
  reduce1_kernel <<<256,          256, 0, stream>>>(S1, b6, h6b);
  gemm2_kernel   <<<dim3(16, 8),  256, 0, stream>>>(h6b, w7, S2);
  reduce2_kernel <<<256,          256, 0, stream>>>(S2, b7, out);
}